// Round 4
// baseline (446.037 us; speedup 1.0000x reference)
//
#include <hip/hip_runtime.h>
#include <hip/hip_bf16.h>

#define SEQ   128
#define BATCH 64
#define EMB   128
#define CELL  128
#define VOCAB 10000
#define NPADV 10240          // vocab rows padded to /64
#define ROWS  8192           // SEQ*BATCH
#define GATES 512            // 4*CELL
#define INDIM 256            // EMB+CELL (gate weight row stride)

typedef short  short8 __attribute__((ext_vector_type(8)));
typedef float  f32x4  __attribute__((ext_vector_type(4)));
typedef unsigned short u16;

static __device__ __forceinline__ u16 f2bf(float f) {
  union { float f; unsigned int u; } v; v.f = f;
  unsigned int u = v.u;
  return (u16)((u + 0x7fffu + ((u >> 16) & 1u)) >> 16);   // RNE
}
static __device__ __forceinline__ float fexp(float x) {
  return __builtin_amdgcn_exp2f(x * 1.44269504088896340736f);
}
static __device__ __forceinline__ float fsig(float x) {
  return __builtin_amdgcn_rcpf(1.0f + fexp(-x));
}
static __device__ __forceinline__ float ftanh(float x) {
  float e = fexp(2.0f * x);                 // e^(2x); overflows to inf -> returns 1 (ok)
  return 1.0f - 2.0f * __builtin_amdgcn_rcpf(e + 1.0f);
}

// ---------- prep kernels ----------
__global__ void k_convert_W(const float* __restrict__ W, u16* __restrict__ Wbf) {
  int idx = blockIdx.x * blockDim.x + threadIdx.x;
  if (idx >= NPADV * EMB) return;
  int v = idx >> 7, k = idx & 127;
  float val = (v < VOCAB) ? W[(size_t)v * EMB + k] : 0.f;
  Wbf[idx] = f2bf(val);
}

// Wall = x-part (cols 0..127) of gate weights, Whb = h-part (cols 128..255), both bf16
__global__ void k_build_gates(const float* __restrict__ Wc, const float* __restrict__ Bc,
                              const float* __restrict__ Wf, const float* __restrict__ Bf,
                              const float* __restrict__ Wi, const float* __restrict__ Bi,
                              const float* __restrict__ Wo, const float* __restrict__ Bo,
                              u16* __restrict__ Wall, u16* __restrict__ Whb,
                              float* __restrict__ Ball) {
  int idx = blockIdx.x * blockDim.x + threadIdx.x;
  if (idx < GATES * EMB) {
    int r = idx >> 7, k = idx & 127;
    int g = r >> 7, j = r & 127;
    const float* Wg = (g == 0) ? Wc : (g == 1) ? Wf : (g == 2) ? Wi : Wo;
    Wall[idx] = f2bf(Wg[(size_t)j * INDIM + k]);
    Whb[idx]  = f2bf(Wg[(size_t)j * INDIM + EMB + k]);
  }
  if (idx < GATES) {
    int g = idx >> 7, j = idx & 127;
    const float* Bg = (g == 0) ? Bc : (g == 1) ? Bf : (g == 2) ? Bi : Bo;
    Ball[idx] = Bg[j];
  }
}

__global__ void k_gather_xe(const int* __restrict__ x, const float* __restrict__ emb,
                            u16* __restrict__ Xe) {
  int idx = blockIdx.x * blockDim.x + threadIdx.x;
  if (idx >= ROWS * EMB) return;
  int c = idx >> 7, e = idx & 127;
  int tok = x[c];                                         // x is [SEQ][BATCH], c = t*64+b
  Xe[idx] = f2bf(emb[(size_t)tok * EMB + e]);
}

// ---------- small bf16 MFMA GEMM (Zin): out[row][col] = A[row]·B[col] + bias[col] ----------
__launch_bounds__(256)
__global__ void k_gemm(const u16* __restrict__ A, const u16* __restrict__ B,
                       const float* __restrict__ bias, float* __restrict__ out,
                       int Nout) {
  __shared__ float tile[64][68];
  int lane = threadIdx.x & 63;
  int wave = threadIdx.x >> 6;
  int lr = lane & 15;
  int kh = lane >> 4;
  int rowbase = blockIdx.y * 64;
  int colblk  = blockIdx.x * 64;
  int colbase = colblk + wave * 16;

  const short8* A8 = (const short8*)A;
  const short8* B8 = (const short8*)B;

  f32x4 acc[4] = {};
#pragma unroll
  for (int ks = 0; ks < 4; ++ks) {
    short8 bfrag = B8[(size_t)(colbase + lr) * 16 + ks * 4 + kh];
#pragma unroll
    for (int m = 0; m < 4; ++m) {
      short8 afrag = A8[(size_t)(rowbase + m * 16 + lr) * 16 + ks * 4 + kh];
      acc[m] = __builtin_amdgcn_mfma_f32_16x16x32_bf16(afrag, bfrag, acc[m], 0, 0, 0);
    }
  }

#pragma unroll
  for (int m = 0; m < 4; ++m)
#pragma unroll
    for (int q = 0; q < 4; ++q)
      tile[m * 16 + kh * 4 + q][wave * 16 + lr] = acc[m][q];
  __syncthreads();

  int col4 = lane & 15;
  int c = colblk + col4 * 4;
  if (c < Nout) {
    f32x4 bv = {};
    if (bias) bv = *(const f32x4*)(bias + c);
#pragma unroll
    for (int i = 0; i < 4; ++i) {
      int r = wave * 16 + i * 4 + (lane >> 4);
      f32x4 v = *(const f32x4*)(&tile[r][col4 * 4]);
      v += bv;
      *(f32x4*)(out + (size_t)(rowbase + r) * Nout + c) = v;
    }
  }
}

// ---------- vocab projection v2: fill-like low occupancy, zero barriers ----------
// 256 blocks (1/CU), 4 waves each. Wave owns 16 rows x 5120 cols, walks 64-col
// groups; B-frags double-buffered in registers (loads g+1 before MFMA g); stores
// issued continuously straight from acc (no LDS, no syncthreads anywhere).
__launch_bounds__(256, 1)
__global__ void k_vocab2(const u16* __restrict__ A, const u16* __restrict__ B,
                         const float* __restrict__ bias, float* __restrict__ out) {
  int tid = threadIdx.x;
  int lane = tid & 63, wv = tid >> 6;
  int lr = lane & 15, kh = lane >> 4;
  int rowbase = blockIdx.x * 32 + (wv >> 1) * 16;
  int chalf = (wv & 1) * (NPADV / 2);

  const short8* A8 = (const short8*)A;
  const short8* B8 = (const short8*)B;

  short8 af[4];
#pragma unroll
  for (int ks = 0; ks < 4; ++ks)
    af[ks] = A8[(size_t)(rowbase + lr) * 16 + ks * 4 + kh];

  short8 bf[16];
#pragma unroll
  for (int cf = 0; cf < 4; ++cf)
#pragma unroll
    for (int ks = 0; ks < 4; ++ks)
      bf[cf * 4 + ks] = B8[(size_t)(chalf + cf * 16 + lr) * 16 + ks * 4 + kh];

  for (int g = 0; g < 80; ++g) {
    short8 bn[16];
    if (g + 1 < 80) {
      int cb = chalf + (g + 1) * 64;
#pragma unroll
      for (int cf = 0; cf < 4; ++cf)
#pragma unroll
        for (int ks = 0; ks < 4; ++ks)
          bn[cf * 4 + ks] = B8[(size_t)(cb + cf * 16 + lr) * 16 + ks * 4 + kh];
    }

    f32x4 acc[4] = {{}, {}, {}, {}};
#pragma unroll
    for (int ks = 0; ks < 4; ++ks)        // ks outer: 4 independent chains interleave
#pragma unroll
      for (int cf = 0; cf < 4; ++cf)
        acc[cf] = __builtin_amdgcn_mfma_f32_16x16x32_bf16(af[ks], bf[cf * 4 + ks], acc[cf], 0, 0, 0);

    int colb = chalf + g * 64;
#pragma unroll
    for (int cf = 0; cf < 4; ++cf) {
      int col = colb + cf * 16 + lr;
      if (col < VOCAB) {
        float bv = bias[col];
#pragma unroll
        for (int q = 0; q < 4; ++q)
          out[(size_t)(rowbase + kh * 4 + q) * VOCAB + col] = acc[cf][q] + bv;
      }
    }
#pragma unroll
    for (int i = 0; i < 16; ++i) bf[i] = bn[i];
  }
}

// ---------- MFMA LSTM recurrence: 4 blocks x 16 batches, 1024 thr (16 waves) ----------
// Per step: Zh[512,16] = Whb[512,128] @ H^T[128,16] via 8 MFMA/wave; H kept bf16 in
// LDS [batch][k] so one ds_read_b128 = a whole B-fragment; activations spread over
// all 1024 threads; Zin (x-part preact + bias) prefetched one step ahead.
__launch_bounds__(1024, 1)
__global__ void k_recur2(const u16* __restrict__ Whb, const float* __restrict__ Zin,
                         u16* __restrict__ Hbf, float* __restrict__ outHC) {
  __shared__ u16   Hb[16 * 136];            // [batch][k] bf16, row stride 272B (16B-aligned)
  __shared__ float zact[512 * 17];          // [gate-row][batch], stride 17 (2-way banks)

  int tid = threadIdx.x;
  int bb = blockIdx.x;                      // batch group: batches bb*16..+15
  int lane = tid & 63, wv = tid >> 6;       // 16 waves
  int lr = lane & 15, kh = lane >> 4;
  int wvbase = wv * 32;                     // this wave's 32 gate-rows

  const short8* W8 = (const short8*)Whb;
  short8* Hb8 = (short8*)Hb;

  short8 af0[4], af1[4];
#pragma unroll
  for (int ks = 0; ks < 4; ++ks) {
    af0[ks] = W8[(size_t)(wvbase + lr) * 16 + ks * 4 + kh];
    af1[ks] = W8[(size_t)(wvbase + 16 + lr) * 16 + ks * 4 + kh];
  }

  // init H = 0 (bf16 zero is 0x0000), C = 0
#pragma unroll
  for (int i = 0; i < 3; ++i) {
    int idx = tid + i * 1024;
    if (idx < 16 * 136) Hb[idx] = 0;
  }
  float c0 = 0.f, c1 = 0.f;

  // prefetch Zin for t=0
  float zpre[8];
#pragma unroll
  for (int t2 = 0; t2 < 2; ++t2)
#pragma unroll
    for (int q = 0; q < 4; ++q) {
      int R = wvbase + t2 * 16 + kh * 4 + q;
      zpre[t2 * 4 + q] = Zin[(size_t)(bb * 16 + lr) * GATES + R];
    }
  __syncthreads();

  for (int t = 0; t < SEQ; ++t) {
    // ---- phase 1: MFMA + activations (all 16 waves) ----
    f32x4 acc0 = {}, acc1 = {};
#pragma unroll
    for (int ks = 0; ks < 4; ++ks) {
      short8 hb = Hb8[lr * 17 + ks * 4 + kh];     // broadcast-free b-frag read
      acc0 = __builtin_amdgcn_mfma_f32_16x16x32_bf16(af0[ks], hb, acc0, 0, 0, 0);
      acc1 = __builtin_amdgcn_mfma_f32_16x16x32_bf16(af1[ks], hb, acc1, 0, 0, 0);
    }
#pragma unroll
    for (int t2 = 0; t2 < 2; ++t2)
#pragma unroll
      for (int q = 0; q < 4; ++q) {
        int R = wvbase + t2 * 16 + kh * 4 + q;
        float z = (t2 ? acc1[q] : acc0[q]) + zpre[t2 * 4 + q];
        float a = ((R >> 7) == 0) ? ftanh(z) : fsig(z);
        zact[R * 17 + lr] = a;
      }
    // prefetch Zin for t+1 (lands during phase 2 + barrier)
    if (t + 1 < SEQ) {
      size_t base = (size_t)((t + 1) * BATCH + bb * 16 + lr) * GATES;
#pragma unroll
      for (int t2 = 0; t2 < 2; ++t2)
#pragma unroll
        for (int q = 0; q < 4; ++q)
          zpre[t2 * 4 + q] = Zin[base + wvbase + t2 * 16 + kh * 4 + q];
    }
    __syncthreads();

    // ---- phase 2: cell update, 2 (cell,batch) pairs per thread ----
    int j = tid & 127, p = tid >> 7;              // p in 0..7; pairs p and p+8
    {
      float Cc = zact[j * 17 + p];
      float F  = zact[(128 + j) * 17 + p];
      float I  = zact[(256 + j) * 17 + p];
      float O  = zact[(384 + j) * 17 + p];
      c0 = F * c0 + I * Cc;
      float H = ftanh(c0) * O;
      u16 h16 = f2bf(H);
      Hb[p * 136 + j] = h16;
      Hbf[(size_t)(t * BATCH + bb * 16 + p) * CELL + j] = h16;
      if (t == SEQ - 1) {
        outHC[(size_t)j * BATCH + bb * 16 + p] = H;
        outHC[(size_t)CELL * BATCH + (size_t)j * BATCH + bb * 16 + p] = c0;
      }
    }
    {
      int p2 = p + 8;
      float Cc = zact[j * 17 + p2];
      float F  = zact[(128 + j) * 17 + p2];
      float I  = zact[(256 + j) * 17 + p2];
      float O  = zact[(384 + j) * 17 + p2];
      c1 = F * c1 + I * Cc;
      float H = ftanh(c1) * O;
      u16 h16 = f2bf(H);
      Hb[p2 * 136 + j] = h16;
      Hbf[(size_t)(t * BATCH + bb * 16 + p2) * CELL + j] = h16;
      if (t == SEQ - 1) {
        outHC[(size_t)j * BATCH + bb * 16 + p2] = H;
        outHC[(size_t)CELL * BATCH + (size_t)j * BATCH + bb * 16 + p2] = c1;
      }
    }
    __syncthreads();
  }
}

extern "C" void kernel_launch(void* const* d_in, const int* in_sizes, int n_in,
                              void* d_out, int out_size, void* d_ws, size_t ws_size,
                              hipStream_t stream) {
  const int*   x   = (const int*)d_in[0];
  const float* emb = (const float*)d_in[1];
  const float* Wc  = (const float*)d_in[2];
  const float* Bc  = (const float*)d_in[3];
  const float* Wf  = (const float*)d_in[4];
  const float* Bf  = (const float*)d_in[5];
  const float* Wi  = (const float*)d_in[6];
  const float* Bi  = (const float*)d_in[7];
  const float* Wo  = (const float*)d_in[8];
  const float* Bo  = (const float*)d_in[9];
  const float* W   = (const float*)d_in[10];
  const float* b   = (const float*)d_in[11];
  float* out = (float*)d_out;

  char* ws = (char*)d_ws;
  size_t off = 0;
  auto alloc = [&](size_t bytes) -> void* {
    void* p = ws + off;
    off = (off + bytes + 255) & ~(size_t)255;
    return p;
  };
  u16*   Wbf  = (u16*)  alloc((size_t)NPADV * EMB * 2);   // 2.56 MB
  u16*   Wall = (u16*)  alloc((size_t)GATES * EMB * 2);   // 128 KB
  u16*   Whb  = (u16*)  alloc((size_t)GATES * CELL * 2);  // 128 KB
  float* Ball = (float*)alloc((size_t)GATES * 4);         // 2 KB
  u16*   Xe   = (u16*)  alloc((size_t)ROWS * EMB * 2);    // 2 MB
  u16*   Hbf  = (u16*)  alloc((size_t)ROWS * CELL * 2);   // 2 MB
  float* Zin  = (float*)alloc((size_t)ROWS * GATES * 4);  // 16 MB

  hipLaunchKernelGGL(k_convert_W, dim3((NPADV * EMB + 255) / 256), dim3(256), 0, stream,
                     W, Wbf);
  hipLaunchKernelGGL(k_build_gates, dim3((GATES * EMB + 255) / 256), dim3(256), 0, stream,
                     Wc, Bc, Wf, Bf, Wi, Bi, Wo, Bo, Wall, Whb, Ball);
  hipLaunchKernelGGL(k_gather_xe, dim3((ROWS * EMB + 255) / 256), dim3(256), 0, stream,
                     x, emb, Xe);
  // Zin[c][r] = Xe[c]·Wall[r] + Ball[r]
  hipLaunchKernelGGL(k_gemm, dim3(GATES / 64, ROWS / 64), dim3(256), 0, stream,
                     Xe, Wall, Ball, Zin, GATES);
  // MFMA recurrence: 4 blocks x 16 batches
  hipLaunchKernelGGL(k_recur2, dim3(BATCH / 16), dim3(1024), 0, stream,
                     Whb, Zin, Hbf, out + (size_t)ROWS * VOCAB);
  // out[c][v] = Hbf[c]·Wbf[v] + b[v]  (fill-like low-occupancy streaming GEMM)
  hipLaunchKernelGGL(k_vocab2, dim3(ROWS / 32), dim3(256), 0, stream,
                     Hbf, Wbf, b, out);
}

// Round 5
// 267.157 us; speedup vs baseline: 1.6696x; 1.6696x over previous
//
#include <hip/hip_runtime.h>
#include <hip/hip_bf16.h>

#define SEQ   128
#define BATCH 64
#define EMB   128
#define CELL  128
#define VOCAB 10000
#define NPADV 10240          // vocab rows padded to /64
#define ROWS  8192           // SEQ*BATCH
#define GATES 512            // 4*CELL
#define INDIM 256            // EMB+CELL (gate weight row stride)

typedef short  short8 __attribute__((ext_vector_type(8)));
typedef float  f32x4  __attribute__((ext_vector_type(4)));
typedef unsigned short u16;

static __device__ __forceinline__ u16 f2bf(float f) {
  union { float f; unsigned int u; } v; v.f = f;
  unsigned int u = v.u;
  return (u16)((u + 0x7fffu + ((u >> 16) & 1u)) >> 16);   // RNE
}
static __device__ __forceinline__ float fexp(float x) {
  return __builtin_amdgcn_exp2f(x * 1.44269504088896340736f);
}
static __device__ __forceinline__ float fsig(float x) {
  return __builtin_amdgcn_rcpf(1.0f + fexp(-x));
}
static __device__ __forceinline__ float ftanh(float x) {
  float e = fexp(2.0f * x);                 // e^(2x); overflows to inf -> returns 1 (ok)
  return 1.0f - 2.0f * __builtin_amdgcn_rcpf(e + 1.0f);
}

// ---------- prep kernels ----------
__global__ void k_convert_W(const float* __restrict__ W, u16* __restrict__ Wbf) {
  int idx = blockIdx.x * blockDim.x + threadIdx.x;
  if (idx >= NPADV * EMB) return;
  int v = idx >> 7, k = idx & 127;
  float val = (v < VOCAB) ? W[(size_t)v * EMB + k] : 0.f;
  Wbf[idx] = f2bf(val);
}

__global__ void k_build_gates(const float* __restrict__ Wc, const float* __restrict__ Bc,
                              const float* __restrict__ Wf, const float* __restrict__ Bf,
                              const float* __restrict__ Wi, const float* __restrict__ Bi,
                              const float* __restrict__ Wo, const float* __restrict__ Bo,
                              u16* __restrict__ Wall, float* __restrict__ Ball) {
  int idx = blockIdx.x * blockDim.x + threadIdx.x;
  if (idx < GATES * EMB) {
    int r = idx >> 7, k = idx & 127;
    int g = r >> 7, j = r & 127;
    const float* Wg = (g == 0) ? Wc : (g == 1) ? Wf : (g == 2) ? Wi : Wo;
    Wall[idx] = f2bf(Wg[(size_t)j * INDIM + k]);          // embedding-part columns 0..127
  }
  if (idx < GATES) {
    int g = idx >> 7, j = idx & 127;
    const float* Bg = (g == 0) ? Bc : (g == 1) ? Bf : (g == 2) ? Bi : Bo;
    Ball[idx] = Bg[j];
  }
}

__global__ void k_gather_xe(const int* __restrict__ x, const float* __restrict__ emb,
                            u16* __restrict__ Xe) {
  int idx = blockIdx.x * blockDim.x + threadIdx.x;
  if (idx >= ROWS * EMB) return;
  int c = idx >> 7, e = idx & 127;
  int tok = x[c];                                         // x is [SEQ][BATCH], c = t*64+b
  Xe[idx] = f2bf(emb[(size_t)tok * EMB + e]);
}

// ---------- small bf16 MFMA GEMM (Zin): out[row][col] = A[row]·B[col] + bias[col] ----------
__launch_bounds__(256)
__global__ void k_gemm(const u16* __restrict__ A, const u16* __restrict__ B,
                       const float* __restrict__ bias, float* __restrict__ out,
                       int Nout) {
  __shared__ float tile[64][68];
  int lane = threadIdx.x & 63;
  int wave = threadIdx.x >> 6;
  int lr = lane & 15;
  int kh = lane >> 4;
  int rowbase = blockIdx.y * 64;
  int colblk  = blockIdx.x * 64;
  int colbase = colblk + wave * 16;

  const short8* A8 = (const short8*)A;
  const short8* B8 = (const short8*)B;

  f32x4 acc[4] = {};
#pragma unroll
  for (int ks = 0; ks < 4; ++ks) {
    short8 bfrag = B8[(size_t)(colbase + lr) * 16 + ks * 4 + kh];
#pragma unroll
    for (int m = 0; m < 4; ++m) {
      short8 afrag = A8[(size_t)(rowbase + m * 16 + lr) * 16 + ks * 4 + kh];
      acc[m] = __builtin_amdgcn_mfma_f32_16x16x32_bf16(afrag, bfrag, acc[m], 0, 0, 0);
    }
  }

#pragma unroll
  for (int m = 0; m < 4; ++m)
#pragma unroll
    for (int q = 0; q < 4; ++q)
      tile[m * 16 + kh * 4 + q][wave * 16 + lr] = acc[m][q];
  __syncthreads();

  int col4 = lane & 15;
  int c = colblk + col4 * 4;
  if (c < Nout) {
    f32x4 bv = {};
    if (bias) bv = *(const f32x4*)(bias + c);
#pragma unroll
    for (int i = 0; i < 4; ++i) {
      int r = wave * 16 + i * 4 + (lane >> 4);
      f32x4 v = *(const f32x4*)(&tile[r][col4 * 4]);
      v += bv;
      *(f32x4*)(out + (size_t)(rowbase + r) * Nout + c) = v;
    }
  }
}

// ---------- vocab projection v3: operand-swapped MFMA, register-direct stores ----------
// acc = mfma(vocab_frag, row_frag): lane holds 4 CONSECUTIVE vocab cols (kh*4+q) of
// ONE output row (lane&15) -> f32x4 store straight from acc. No LDS, no barriers.
// Stores issue every ~8 MFMA continuously -> large in-flight write volume (Little's
// law: prior variants capped at 1.7 TB/s because stores were confined to short
// epilogue phases). 1024 blocks = 32-row band x 4 col-slices, 4 blocks/CU.
__launch_bounds__(256, 4)
__global__ void k_vocab3(const u16* __restrict__ A, const u16* __restrict__ B,
                         const float* __restrict__ bias, float* __restrict__ out) {
  int tid = threadIdx.x;
  int lane = tid & 63, wv = tid >> 6;
  int lr = lane & 15, kh = lane >> 4;
  int band  = blockIdx.x >> 2;            // 256 bands of 32 rows
  int slice = blockIdx.x & 3;             // 4 col-slices of 2560
  int rowbase = band * 32;
  int colbase = slice * 2560 + wv * 640;  // this wave: 40 groups of 16 cols

  const short8* A8 = (const short8*)A;
  const short8* B8 = (const short8*)B;

  short8 af0[4], af1[4];
#pragma unroll
  for (int ks = 0; ks < 4; ++ks) {
    af0[ks] = A8[(size_t)(rowbase + lr) * 16 + ks * 4 + kh];
    af1[ks] = A8[(size_t)(rowbase + 16 + lr) * 16 + ks * 4 + kh];
  }

  short8 vf[2][4];
  f32x4 bv[2];
#pragma unroll
  for (int ks = 0; ks < 4; ++ks)
    vf[0][ks] = B8[(size_t)(colbase + lr) * 16 + ks * 4 + kh];
  bv[0] = *(const f32x4*)(bias + colbase + kh * 4);

  for (int g = 0; g < 40; ++g) {
    int cur = g & 1, nxt = cur ^ 1;
    if (g + 1 < 40) {
      int cg = colbase + (g + 1) * 16;
#pragma unroll
      for (int ks = 0; ks < 4; ++ks)
        vf[nxt][ks] = B8[(size_t)(cg + lr) * 16 + ks * 4 + kh];
      bv[nxt] = *(const f32x4*)(bias + cg + kh * 4);
    }

    f32x4 a0 = {}, a1 = {};
#pragma unroll
    for (int ks = 0; ks < 4; ++ks) {
      a0 = __builtin_amdgcn_mfma_f32_16x16x32_bf16(vf[cur][ks], af0[ks], a0, 0, 0, 0);
      a1 = __builtin_amdgcn_mfma_f32_16x16x32_bf16(vf[cur][ks], af1[ks], a1, 0, 0, 0);
    }

    int colg = colbase + g * 16;
    if (colg < VOCAB) {                   // VOCAB%16==0: whole group valid or not
      int c = colg + kh * 4;
      a0 += bv[cur];
      a1 += bv[cur];
      *(f32x4*)(out + (size_t)(rowbase + lr) * VOCAB + c) = a0;
      *(f32x4*)(out + (size_t)(rowbase + 16 + lr) * VOCAB + c) = a1;
    }
  }
}

// ---------- sequential LSTM recurrence: one workgroup per batch column ----------
// 512 threads; thread r owns gate row r. Wh row (128 f32) in VGPRs; H broadcast via
// v_readlane. Zin prefetched 2 steps ahead (hides ~900cy HBM/L3 latency per step).
__launch_bounds__(512, 2)
__global__ void k_recur(const float* __restrict__ Wc, const float* __restrict__ Wf,
                        const float* __restrict__ Wi, const float* __restrict__ Wo,
                        const float* __restrict__ Zin, u16* __restrict__ Hbf,
                        float* __restrict__ outHC) {
  __shared__ float Hl[CELL];
  __shared__ float zl[GATES];
  int tid = threadIdx.x;
  int b = blockIdx.x;
  int lane = tid & 63;
  int g = tid >> 7, j = tid & 127;
  const float* Wg = (g == 0) ? Wc : (g == 1) ? Wf : (g == 2) ? Wi : Wo;
  const float* wp = Wg + (size_t)j * INDIM + EMB;

  float w[128];
#pragma unroll
  for (int k = 0; k < 128; ++k) w[k] = wp[k];

  if (tid < CELL) Hl[tid] = 0.f;
  float C = 0.f;

  // rolling depth-2 Zin prefetch
  float zcur = Zin[(size_t)(0 * BATCH + b) * GATES + tid];
  float znxt = Zin[(size_t)(1 * BATCH + b) * GATES + tid];
  __syncthreads();

  for (int t = 0; t < SEQ; ++t) {
    float zv = zcur;
    zcur = znxt;
    if (t + 2 < SEQ)
      znxt = Zin[(size_t)((t + 2) * BATCH + b) * GATES + tid];

    float h0 = Hl[lane];
    float h1 = Hl[lane + 64];
    float a0 = 0.f, a1 = 0.f, a2 = 0.f, a3 = 0.f;
#pragma unroll
    for (int k = 0; k < 32; ++k) {
      float p0 = __uint_as_float(__builtin_amdgcn_readlane(__float_as_uint(h0), k));
      a0 += w[k] * p0;
      float p1 = __uint_as_float(__builtin_amdgcn_readlane(__float_as_uint(h0), k + 32));
      a1 += w[k + 32] * p1;
      float p2 = __uint_as_float(__builtin_amdgcn_readlane(__float_as_uint(h1), k));
      a2 += w[k + 64] * p2;
      float p3 = __uint_as_float(__builtin_amdgcn_readlane(__float_as_uint(h1), k + 32));
      a3 += w[k + 96] * p3;
    }
    zl[tid] = zv + (a0 + a1) + (a2 + a3);
    __syncthreads();
    int c = t * BATCH + b;
    if (tid < CELL) {
      float cand = ftanh(zl[tid]);
      float F = fsig(zl[CELL + tid]);
      float I = fsig(zl[2 * CELL + tid]);
      float O = fsig(zl[3 * CELL + tid]);
      C = F * C + I * cand;
      float H = ftanh(C) * O;
      Hl[tid] = H;
      Hbf[(size_t)c * CELL + tid] = f2bf(H);
      if (t == SEQ - 1) {
        outHC[(size_t)tid * BATCH + b] = H;
        outHC[(size_t)CELL * BATCH + (size_t)tid * BATCH + b] = C;
      }
    }
    __syncthreads();
  }
}

extern "C" void kernel_launch(void* const* d_in, const int* in_sizes, int n_in,
                              void* d_out, int out_size, void* d_ws, size_t ws_size,
                              hipStream_t stream) {
  const int*   x   = (const int*)d_in[0];
  const float* emb = (const float*)d_in[1];
  const float* Wc  = (const float*)d_in[2];
  const float* Bc  = (const float*)d_in[3];
  const float* Wf  = (const float*)d_in[4];
  const float* Bf  = (const float*)d_in[5];
  const float* Wi  = (const float*)d_in[6];
  const float* Bi  = (const float*)d_in[7];
  const float* Wo  = (const float*)d_in[8];
  const float* Bo  = (const float*)d_in[9];
  const float* W   = (const float*)d_in[10];
  const float* b   = (const float*)d_in[11];
  float* out = (float*)d_out;

  char* ws = (char*)d_ws;
  size_t off = 0;
  auto alloc = [&](size_t bytes) -> void* {
    void* p = ws + off;
    off = (off + bytes + 255) & ~(size_t)255;
    return p;
  };
  u16*   Wbf  = (u16*)  alloc((size_t)NPADV * EMB * 2);   // 2.56 MB
  u16*   Wall = (u16*)  alloc((size_t)GATES * EMB * 2);   // 128 KB
  float* Ball = (float*)alloc((size_t)GATES * 4);         // 2 KB
  u16*   Xe   = (u16*)  alloc((size_t)ROWS * EMB * 2);    // 2 MB
  u16*   Hbf  = (u16*)  alloc((size_t)ROWS * CELL * 2);   // 2 MB
  float* Zin  = (float*)alloc((size_t)ROWS * GATES * 4);  // 16 MB

  hipLaunchKernelGGL(k_convert_W, dim3((NPADV * EMB + 255) / 256), dim3(256), 0, stream,
                     W, Wbf);
  hipLaunchKernelGGL(k_build_gates, dim3((GATES * EMB + 255) / 256), dim3(256), 0, stream,
                     Wc, Bc, Wf, Bf, Wi, Bi, Wo, Bo, Wall, Ball);
  hipLaunchKernelGGL(k_gather_xe, dim3((ROWS * EMB + 255) / 256), dim3(256), 0, stream,
                     x, emb, Xe);
  // Zin[c][r] = Xe[c]·Wall[r] + Ball[r]
  hipLaunchKernelGGL(k_gemm, dim3(GATES / 64, ROWS / 64), dim3(256), 0, stream,
                     Xe, Wall, Ball, Zin, GATES);
  // sequential recurrence, writes Hbf + final Ht/Ct
  hipLaunchKernelGGL(k_recur, dim3(BATCH), dim3(512), 0, stream,
                     Wc, Wf, Wi, Wo, Zin, Hbf, out + (size_t)ROWS * VOCAB);
  // out[c][v] = Hbf[c]·Wbf[v] + b[v]  (register-direct streaming stores)
  hipLaunchKernelGGL(k_vocab3, dim3(1024), dim3(256), 0, stream,
                     Hbf, Wbf, b, out);
}